// Round 8
// baseline (316.793 us; speedup 1.0000x reference)
//
#include <hip/hip_runtime.h>
#include <hip/hip_bf16.h>
#include <hip/hip_fp8.h>
#include <stdint.h>

#define D_DIM 2048
#define B_TOK 4096
#define COEF (2.0f / 8388608.0f)   // 2/(B*D)

typedef __bf16 bf16x8 __attribute__((ext_vector_type(8)));
typedef float  f32x4  __attribute__((ext_vector_type(4)));
typedef int    i32x8  __attribute__((ext_vector_type(8)));

__device__ __forceinline__ unsigned short f2bf(float f) {
  return __builtin_bit_cast(unsigned short, (__bf16)f);
}
__device__ __forceinline__ float bf2f(unsigned short u) {
  return (float)__builtin_bit_cast(__bf16, u);
}
__device__ __forceinline__ unsigned char f2f8(float f) {
  __hip_fp8_e4m3 v(f);            // OCP e4m3fn, RNE + satfinite
  return v.__x;
}

// async global->LDS, 16B per lane; LDS dest = wave-uniform base + lane*16
__device__ __forceinline__ void async16(const void* g, void* l) {
  __builtin_amdgcn_global_load_lds(
      (__attribute__((address_space(1))) void*)(g),
      (__attribute__((address_space(3))) void*)(l),
      16, 0, 0);
}

// ---------------------------------------------------------------------------
// BF16 big-tile core, single-barrier counted-wait schedule (BEST measured):
// C[256x128], BK=64, 8 waves (4M x 2N), per-wave 64x64 = 4x4 of
// mfma_f32_16x16x32_bf16.
// Per K-tile: issue ALL 16 ds_read_b128 (slice0 8, slice1 8) -> stage kt+2
// -> lgkmcnt(8) -> 16 MFMA (slice0, overlapping slice1's LDS drain)
// -> lgkmcnt(0) -> 16 MFMA (slice1) -> vmcnt(6) -> ONE s_barrier.
// Invariants:
//  - WAR: buffer (kt+2)%3 was read in iter kt-1; every wave lgkm-drains its
//    reads before reaching barrier(kt-1), and stage(kt+2) is issued after
//    that barrier => safe.
//  - publish: own vmcnt(6) at end of iter kt completes tile kt+1's 6 loads
//    (kt+2's 6 stay in flight); barrier makes them visible to all waves.
// ---------------------------------------------------------------------------
__device__ __forceinline__ void gemm_core_256(const unsigned short* __restrict__ Ablk,
                                              const unsigned short* __restrict__ Bblk,
                                              const int lda, const int ldb, const int KC,
                                              unsigned short* As, unsigned short* Bs,
                                              f32x4 acc[4][4]) {
  const int tid  = threadIdx.x;
  const int lane = tid & 63;
  const int wv   = tid >> 6;          // 0..7
  const int wm   = wv >> 1;           // 0..3 (M)
  const int wn   = wv & 1;            // 0..1 (N)
  const int t    = lane & 15;
  const int quad = lane >> 4;
  const int lrow = lane >> 3;
  const int kq   = lane & 7;
  const int kqs  = kq ^ lrow;

  const int nk = KC >> 6;

  auto stageA2 = [&](int buf, int kt, int l0) {   // 2 A-segments
    const int k0 = kt << 6;
    unsigned short* Ad = As + buf * 16384;
#pragma unroll
    for (int l = l0; l < l0 + 2; ++l) {
      const int seg = wv * 4 + l;
      const int r   = seg * 8 + lrow;
      async16(Ablk + (size_t)r * lda + k0 + kqs * 8, Ad + seg * 512);
    }
  };
  auto stageB1 = [&](int buf, int kt, int l) {    // 1 B-segment
    const int k0 = kt << 6;
    unsigned short* Bd = Bs + buf * 8192;
    const int seg = wv * 2 + l;
    const int r   = seg * 8 + lrow;
    async16(Bblk + (size_t)r * ldb + k0 + kqs * 8, Bd + seg * 512);
  };

  // prologue: stage tiles 0 and 1 (6 loads each), publish tile 0
  stageA2(0, 0, 0); stageA2(0, 0, 2); stageB1(0, 0, 0); stageB1(0, 0, 1);
  if (nk > 1) { stageA2(1, 1, 0); stageA2(1, 1, 2); stageB1(1, 1, 0); stageB1(1, 1, 1); }
  if (nk > 1) asm volatile("s_waitcnt vmcnt(6)" ::: "memory");
  else        asm volatile("s_waitcnt vmcnt(0)" ::: "memory");
  __builtin_amdgcn_s_barrier();

  int cur = 0;
  for (int kt = 0; kt < nk; ++kt) {
    const unsigned short* Ac = As + cur * 16384;
    const unsigned short* Bc = Bs + cur * 8192;
    const int nb = (cur >= 1) ? cur - 1 : 2;      // (cur+2)%3
    const bool pf = (kt + 2 < nk);

    bf16x8 af0[4], bf0[4], af1[4], bf1[4];
    // slice 0 reads (first 8 lgkm ops)
#pragma unroll
    for (int i = 0; i < 4; ++i) {
      const int rm = wm * 64 + i * 16 + t;
      const int rn = wn * 64 + i * 16 + t;
      af0[i] = *(const bf16x8*)(Ac + rm * 64 + ((quad) ^ (rm & 7)) * 8);
      bf0[i] = *(const bf16x8*)(Bc + rn * 64 + ((quad) ^ (rn & 7)) * 8);
    }
    __builtin_amdgcn_sched_barrier(0);
    // slice 1 reads (next 8 lgkm ops)
#pragma unroll
    for (int i = 0; i < 4; ++i) {
      const int rm = wm * 64 + i * 16 + t;
      const int rn = wn * 64 + i * 16 + t;
      af1[i] = *(const bf16x8*)(Ac + rm * 64 + ((4 + quad) ^ (rm & 7)) * 8);
      bf1[i] = *(const bf16x8*)(Bc + rn * 64 + ((4 + quad) ^ (rn & 7)) * 8);
    }
    __builtin_amdgcn_sched_barrier(0);
    if (pf) { stageA2(nb, kt + 2, 0); stageA2(nb, kt + 2, 2);
              stageB1(nb, kt + 2, 0); stageB1(nb, kt + 2, 1); }
    __builtin_amdgcn_sched_barrier(0);
    asm volatile("s_waitcnt lgkmcnt(8)" ::: "memory");   // slice0 landed
    __builtin_amdgcn_sched_barrier(0);
    __builtin_amdgcn_s_setprio(1);
#pragma unroll
    for (int i = 0; i < 4; ++i)
#pragma unroll
      for (int j = 0; j < 4; ++j)
        acc[i][j] = __builtin_amdgcn_mfma_f32_16x16x32_bf16(af0[i], bf0[j], acc[i][j], 0, 0, 0);
    __builtin_amdgcn_s_setprio(0);
    __builtin_amdgcn_sched_barrier(0);
    asm volatile("s_waitcnt lgkmcnt(0)" ::: "memory");   // slice1 landed
    __builtin_amdgcn_sched_barrier(0);
    __builtin_amdgcn_s_setprio(1);
#pragma unroll
    for (int i = 0; i < 4; ++i)
#pragma unroll
      for (int j = 0; j < 4; ++j)
        acc[i][j] = __builtin_amdgcn_mfma_f32_16x16x32_bf16(af1[i], bf1[j], acc[i][j], 0, 0, 0);
    __builtin_amdgcn_s_setprio(0);
    __builtin_amdgcn_sched_barrier(0);
    // publish tile kt+1 (own loads), leave kt+2's 6 in flight
    if (pf)               asm volatile("s_waitcnt vmcnt(6)" ::: "memory");
    else if (kt + 1 < nk) asm volatile("s_waitcnt vmcnt(0)" ::: "memory");
    __builtin_amdgcn_s_barrier();
    cur = (cur == 2) ? 0 : cur + 1;
  }
}

// 256x128 prologue: grid dim3(16,16), 512 threads, XCD-bijective swizzle.
#define GEMM_PROLOGUE256(AP, BP, LDAv, LDBv, KCv)                              \
  __shared__ __align__(16) unsigned short As[3 * 16384];                       \
  __shared__ __align__(16) unsigned short Bs[3 * 8192];                        \
  const int lin = blockIdx.y * 16 + blockIdx.x;                                \
  const int swz = (lin & 7) * 32 + (lin >> 3);                                 \
  const int bx = swz & 15, by = swz >> 4;                                      \
  const unsigned short* Ablk = (AP) + (size_t)by * 256 * (LDAv);               \
  const unsigned short* Bblk = (BP) + (size_t)bx * 128 * (LDBv);               \
  f32x4 acc[4][4];                                                             \
  _Pragma("unroll") for (int i = 0; i < 4; ++i)                                \
  _Pragma("unroll") for (int j = 0; j < 4; ++j)                                \
      acc[i][j] = (f32x4){0.f, 0.f, 0.f, 0.f};                                 \
  gemm_core_256(Ablk, Bblk, (LDAv), (LDBv), (KCv), As, Bs, acc);               \
  const int lane = threadIdx.x & 63;                                           \
  const int wv = threadIdx.x >> 6;                                             \
  const int wm = wv >> 1, wn = wv & 1;                                         \
  const int t = lane & 15, quad = lane >> 4;                                   \
  const int gm_base = by * 256 + wm * 64;                                      \
  const int gn_base = bx * 128 + wn * 64;

// ---------------------------------------------------------------------------
// FP8 MX big-tile core, single-barrier counted-wait schedule + CONFLICT-FREE
// chunk map {quad^x, (4+quad)^x} (K-permutation applied to both A and B =>
// MFMA dot product unchanged; scale=1 everywhere).
// Per K-tile: 16 b128 reads (group0 = af+b0,b1 = 12 ops, group1 = b2,b3 =
// 4 ops) -> stage -> lgkmcnt(4) -> 8 MFMA (j=0,1) -> lgkmcnt(0) ->
// 8 MFMA (j=2,3) -> vmcnt(6) -> ONE barrier.
// ---------------------------------------------------------------------------
__device__ __forceinline__ void gemm_core_f8_256(const unsigned char* __restrict__ Ablk,
                                                 const unsigned char* __restrict__ Bblk,
                                                 const int lda, const int ldb, const int KC,
                                                 unsigned char* As, unsigned char* Bs,
                                                 f32x4 acc[4][4]) {
  const int tid  = threadIdx.x;
  const int lane = tid & 63;
  const int wv   = tid >> 6;          // 0..7
  const int wm   = wv >> 1;           // 0..3 (M)
  const int wn   = wv & 1;            // 0..1 (N)
  const int t    = lane & 15;
  const int quad = lane >> 4;
  const int lrow = lane >> 3;
  const int kq   = lane & 7;
  const int kqs  = kq ^ lrow;

  const int nk = KC >> 7;

  auto stageA2 = [&](int buf, int kt, int l0) {   // 2 A-segments (8 rows each)
    const int k0 = kt << 7;
    unsigned char* Ad = As + buf * 32768;
#pragma unroll
    for (int l = l0; l < l0 + 2; ++l) {
      const int seg = wv * 4 + l;                 // 32 segs total
      const int r   = seg * 8 + lrow;
      async16(Ablk + (size_t)r * lda + k0 + kqs * 16, Ad + seg * 1024);
    }
  };
  auto stageB1 = [&](int buf, int kt, int l) {    // 1 B-segment
    const int k0 = kt << 7;
    unsigned char* Bd = Bs + buf * 16384;
    const int seg = wv * 2 + l;                   // 16 segs total
    const int r   = seg * 8 + lrow;
    async16(Bblk + (size_t)r * ldb + k0 + kqs * 16, Bd + seg * 1024);
  };

  // Conflict-free fragment read: chunks quad^x and (4+quad)^x of a 128B row
  // (empirically-clean bf16 pattern). Lane holds global K-bytes
  // [16*quad,+16) and [64+16*quad,+16): same K-permutation on A and B.
  auto readF = [&](const unsigned char* base, int x) -> i32x8 {
    const uint4 lo = *(const uint4*)(base + ((quad      ) ^ x) * 16);
    const uint4 hi = *(const uint4*)(base + ((4 + quad  ) ^ x) * 16);
    return (i32x8){(int)lo.x, (int)lo.y, (int)lo.z, (int)lo.w,
                   (int)hi.x, (int)hi.y, (int)hi.z, (int)hi.w};
  };

  // prologue: stage tiles 0 and 1 (6 loads each), publish tile 0
  stageA2(0, 0, 0); stageA2(0, 0, 2); stageB1(0, 0, 0); stageB1(0, 0, 1);
  if (nk > 1) { stageA2(1, 1, 0); stageA2(1, 1, 2); stageB1(1, 1, 0); stageB1(1, 1, 1); }
  if (nk > 1) asm volatile("s_waitcnt vmcnt(6)" ::: "memory");
  else        asm volatile("s_waitcnt vmcnt(0)" ::: "memory");
  __builtin_amdgcn_s_barrier();

  int cur = 0;
  for (int kt = 0; kt < nk; ++kt) {
    const unsigned char* Ac = As + cur * 32768;
    const unsigned char* Bc = Bs + cur * 16384;
    const int nb = (cur >= 1) ? cur - 1 : 2;      // (cur+2)%3
    const bool pf = (kt + 2 < nk);

    i32x8 af[4], bq0, bq1, bq2, bq3;
    // group 0: A-frags + B j=0,1 (12 lgkm ops)
#pragma unroll
    for (int i = 0; i < 4; ++i) {
      const int rm = wm * 64 + i * 16 + t;
      af[i] = readF(Ac + rm * 128, rm & 7);
    }
    {
      const int rn0 = wn * 64 + 0 * 16 + t;
      bq0 = readF(Bc + rn0 * 128, rn0 & 7);
      const int rn1 = wn * 64 + 1 * 16 + t;
      bq1 = readF(Bc + rn1 * 128, rn1 & 7);
    }
    __builtin_amdgcn_sched_barrier(0);
    // group 1: B j=2,3 (4 lgkm ops)
    {
      const int rn2 = wn * 64 + 2 * 16 + t;
      bq2 = readF(Bc + rn2 * 128, rn2 & 7);
      const int rn3 = wn * 64 + 3 * 16 + t;
      bq3 = readF(Bc + rn3 * 128, rn3 & 7);
    }
    __builtin_amdgcn_sched_barrier(0);
    if (pf) { stageA2(nb, kt + 2, 0); stageA2(nb, kt + 2, 2);
              stageB1(nb, kt + 2, 0); stageB1(nb, kt + 2, 1); }
    __builtin_amdgcn_sched_barrier(0);
    asm volatile("s_waitcnt lgkmcnt(4)" ::: "memory");   // group0 landed
    __builtin_amdgcn_sched_barrier(0);
    __builtin_amdgcn_s_setprio(1);
#pragma unroll
    for (int i = 0; i < 4; ++i) {
      acc[i][0] = __builtin_amdgcn_mfma_scale_f32_16x16x128_f8f6f4(
          af[i], bq0, acc[i][0], 0, 0, 0, 127, 0, 127);
      acc[i][1] = __builtin_amdgcn_mfma_scale_f32_16x16x128_f8f6f4(
          af[i], bq1, acc[i][1], 0, 0, 0, 127, 0, 127);
    }
    __builtin_amdgcn_s_setprio(0);
    __builtin_amdgcn_sched_barrier(0);
    asm volatile("s_waitcnt lgkmcnt(0)" ::: "memory");   // group1 landed
    __builtin_amdgcn_sched_barrier(0);
    __builtin_amdgcn_s_setprio(1);
#pragma unroll
    for (int i = 0; i < 4; ++i) {
      acc[i][2] = __builtin_amdgcn_mfma_scale_f32_16x16x128_f8f6f4(
          af[i], bq2, acc[i][2], 0, 0, 0, 127, 0, 127);
      acc[i][3] = __builtin_amdgcn_mfma_scale_f32_16x16x128_f8f6f4(
          af[i], bq3, acc[i][3], 0, 0, 0, 127, 0, 127);
    }
    __builtin_amdgcn_s_setprio(0);
    __builtin_amdgcn_sched_barrier(0);
    if (pf)               asm volatile("s_waitcnt vmcnt(6)" ::: "memory");
    else if (kt + 1 < nk) asm volatile("s_waitcnt vmcnt(0)" ::: "memory");
    __builtin_amdgcn_s_barrier();
    cur = (cur == 2) ? 0 : cur + 1;
  }
}

// 256x128 fp8 prologue: 512 threads, grid-size-generic XCD-bijective swizzle
// (all fp8 grids have gridDim.x == 16 and nwg % 8 == 0).
#define GEMM8_PROLOGUE256(AP, BP, LDAv, LDBv, KCv)                             \
  __shared__ __align__(16) unsigned char As8[3 * 32768];                       \
  __shared__ __align__(16) unsigned char Bs8[3 * 16384];                       \
  const int nwg = gridDim.x * gridDim.y;                                       \
  const int lin = blockIdx.y * 16 + blockIdx.x;                                \
  const int swz = (lin & 7) * (nwg >> 3) + (lin >> 3);                         \
  const int bx = swz & 15, by = swz >> 4;                                      \
  const unsigned char* Ablk = (AP) + (size_t)by * 256 * (LDAv);                \
  const unsigned char* Bblk = (BP) + (size_t)bx * 128 * (LDBv);                \
  f32x4 acc[4][4];                                                             \
  _Pragma("unroll") for (int i = 0; i < 4; ++i)                                \
  _Pragma("unroll") for (int j = 0; j < 4; ++j)                                \
      acc[i][j] = (f32x4){0.f, 0.f, 0.f, 0.f};                                 \
  gemm_core_f8_256(Ablk, Bblk, (LDAv), (LDBv), (KCv), As8, Bs8, acc);          \
  const int lane = threadIdx.x & 63;                                           \
  const int wv = threadIdx.x >> 6;                                             \
  const int wm = wv >> 1, wn = wv & 1;                                         \
  const int t = lane & 15, quad = lane >> 4;                                   \
  const int gm_base = by * 256 + wm * 64;                                      \
  const int gn_base = bx * 128 + wn * 64;

// GEMM-train (fp8): train = src @ thk^T. A = src_cat_f8 right half (lda 4096).
// Writes train fp8 into src_cat_f8 LEFT half + trainT8 (LDS-transposed).
__global__ __launch_bounds__(512, 2) void gemm_train_f8(
    const unsigned char* __restrict__ srcA,     // src_cat_f8 + 2048
    const unsigned char* __restrict__ thkT8,    // ld 2048
    unsigned char* __restrict__ src_cat_f8,
    unsigned char* __restrict__ trainT8) {
  GEMM8_PROLOGUE256(srcA, thkT8, 4096, 2048, 2048)
  unsigned char* scr = As8 + wv * 2304;   // per-wave 32 x 72 B scratch
#pragma unroll
  for (int p = 0; p < 2; ++p) {
#pragma unroll
    for (int jl = 0; jl < 2; ++jl) {
      const int j = p * 2 + jl;
      const int gn = gn_base + j * 16 + t;
#pragma unroll
      for (int i = 0; i < 4; ++i) {
        const int gm0 = gm_base + i * 16 + quad * 4;
        uchar4 pk = make_uchar4(f2f8(acc[i][j][0]), f2f8(acc[i][j][1]),
                                f2f8(acc[i][j][2]), f2f8(acc[i][j][3]));
        src_cat_f8[(size_t)(gm0 + 0) * 4096 + gn] = pk.x;
        src_cat_f8[(size_t)(gm0 + 1) * 4096 + gn] = pk.y;
        src_cat_f8[(size_t)(gm0 + 2) * 4096 + gn] = pk.z;
        src_cat_f8[(size_t)(gm0 + 3) * 4096 + gn] = pk.w;
        *(uchar4*)(scr + (jl * 16 + t) * 72 + i * 16 + quad * 4) = pk;
      }
    }
    __syncthreads();
    const int row = lane >> 3, chunk = lane & 7;
#pragma unroll
    for (int q = 0; q < 4; ++q) {
      const int rr = q * 8 + row;
      const uint2 v = *(const uint2*)(scr + rr * 72 + chunk * 8);
      *(uint2*)(trainT8 + (size_t)(gn_base + p * 32 + rr) * B_TOK + gm_base + chunk * 8) = v;
    }
    __syncthreads();
  }
}

// GEMM-test (bf16, 256x128): test = src @ thq^T -> testv (ld 2048)
__global__ __launch_bounds__(512, 2) void gemm_test(
    const unsigned short* __restrict__ src_bf,
    const unsigned short* __restrict__ thqT,
    unsigned short* __restrict__ testv) {
  GEMM_PROLOGUE256(src_bf, thqT, 2048, 2048, 2048)
#pragma unroll
  for (int i = 0; i < 4; ++i) {
#pragma unroll
    for (int j = 0; j < 4; ++j) {
      const int gm0 = gm_base + i * 16 + quad * 4;
      const int gn  = gn_base + j * 16 + t;
#pragma unroll
      for (int r = 0; r < 4; ++r)
        testv[(size_t)(gm0 + r) * D_DIM + gn] = f2bf(acc[i][j][r]);
    }
  }
}

// GEMM-err (fp8, K=4096): err = [train|src] @ [W | (thk-thv)^T]^T + b.
// Stored transposed errT8[D, B_TOK] fp8 + gb column sums.
__global__ __launch_bounds__(512, 2) void gemm_err_f8(
    const unsigned char* __restrict__ src_cat_f8,
    const unsigned char* __restrict__ Wcat_f8,
    const float* __restrict__ bvec,
    unsigned char* __restrict__ errT8,
    float* __restrict__ gb) {
  GEMM8_PROLOGUE256(src_cat_f8, Wcat_f8, 4096, 4096, 4096)
  unsigned char* scr = As8 + wv * 2304;
#pragma unroll
  for (int p = 0; p < 2; ++p) {
#pragma unroll
    for (int jl = 0; jl < 2; ++jl) {
      const int j = p * 2 + jl;
      const int gn = gn_base + j * 16 + t;
      const float bias = bvec[gn];
      float cs = 0.f;
#pragma unroll
      for (int i = 0; i < 4; ++i) {
        const float e0 = acc[i][j][0] + bias, e1 = acc[i][j][1] + bias;
        const float e2 = acc[i][j][2] + bias, e3 = acc[i][j][3] + bias;
        *(uchar4*)(scr + (jl * 16 + t) * 72 + i * 16 + quad * 4) =
            make_uchar4(f2f8(e0), f2f8(e1), f2f8(e2), f2f8(e3));
        cs += e0 + e1 + e2 + e3;
      }
      cs += __shfl_xor(cs, 16);
      cs += __shfl_xor(cs, 32);
      if (quad == 0) atomicAdd(&gb[gn], cs);
    }
    __syncthreads();
    const int row = lane >> 3, chunk = lane & 7;
#pragma unroll
    for (int q = 0; q < 4; ++q) {
      const int rr = q * 8 + row;
      const uint2 v = *(const uint2*)(scr + rr * 72 + chunk * 8);
      *(uint2*)(errT8 + (size_t)(gn_base + p * 32 + rr) * B_TOK + gm_base + chunk * 8) = v;
    }
    __syncthreads();
  }
}

// GEMM-gW (fp8, split-K=2): P_z = errT[:, z*2048:+2048] @ trainT[:, same]^T
__global__ __launch_bounds__(512, 2) void gemm_gw_f8(
    const unsigned char* __restrict__ errT8,
    const unsigned char* __restrict__ trainT8,
    float* __restrict__ P0, float* __restrict__ P1) {
  const int z = blockIdx.z;
  const unsigned char* Abase = errT8 + z * 2048;
  const unsigned char* Bbase = trainT8 + z * 2048;
  GEMM8_PROLOGUE256(Abase, Bbase, B_TOK, B_TOK, 2048)
  float* P = (z == 0) ? P0 : P1;
#pragma unroll
  for (int i = 0; i < 4; ++i) {
#pragma unroll
    for (int j = 0; j < 4; ++j) {
      const int gm0 = gm_base + i * 16 + quad * 4;
      const int gn  = gn_base + j * 16 + t;
#pragma unroll
      for (int r = 0; r < 4; ++r)
        P[(size_t)(gm0 + r) * D_DIM + gn] = acc[i][j][r];
    }
  }
}

// Reduce partials + SGD update: Wnew = bf16(W - lr_w * COEF * (P0+P1))
__global__ __launch_bounds__(256) void wnew_reduce(
    const float* __restrict__ P0, const float* __restrict__ P1,
    const float* __restrict__ W, const float* __restrict__ lr_w,
    unsigned short* __restrict__ Wnew) {
  const int i = blockIdx.x * 256 + threadIdx.x;
  const float4 p0 = ((const float4*)P0)[i];
  const float4 p1 = ((const float4*)P1)[i];
  const float4 w  = ((const float4*)W)[i];
  const float4 l  = ((const float4*)lr_w)[i];
  ((ushort4*)Wnew)[i] = make_ushort4(
      f2bf(w.x - l.x * (COEF * (p0.x + p1.x))),
      f2bf(w.y - l.y * (COEF * (p0.y + p1.y))),
      f2bf(w.z - l.z * (COEF * (p0.z + p1.z))),
      f2bf(w.w - l.w * (COEF * (p0.w + p1.w))));
}

// GEMM-out (bf16, 256x128): z = test @ Wnew^T + b_new + test, b_new inline
__global__ __launch_bounds__(512, 2) void gemm_out(
    const unsigned short* __restrict__ testv,
    const unsigned short* __restrict__ Wnew,
    const float* __restrict__ bvec,
    const float* __restrict__ lr_b,
    const float* __restrict__ gb,
    float* __restrict__ out) {
  GEMM_PROLOGUE256(testv, Wnew, 2048, 2048, 2048)
#pragma unroll
  for (int j = 0; j < 4; ++j) {
    const int gn = gn_base + j * 16 + t;
    const float bias = bvec[gn] - lr_b[gn] * (COEF * gb[gn]);
#pragma unroll
    for (int i = 0; i < 4; ++i) {
      const int gm0 = gm_base + i * 16 + quad * 4;
#pragma unroll
      for (int r = 0; r < 4; ++r) {
        const size_t idx = (size_t)(gm0 + r) * D_DIM + gn;
        out[idx] = acc[i][j][r] + bias + bf2f(testv[idx]);
      }
    }
  }
}

// Fused conversions (one launch, grid dim3(32,32,15), 256 threads):
// z<3: VECTORIZED 64x64 transpose+convert (float4 loads -> LDS[64][65]
//      -> packed uchar4/ushort4 stores; both sides coalesced).
//      z=0: thk^T->thkT8 fp8; z=1: thq^T->thqT bf16;
//      z=2: (thk-thv)^T -> Wcat_f8 right half fp8
// z>=3: elementwise (12 slices x 1024 blocks = old 12288-block cvt):
//      src -> src_bf (bf16) + src_cat_f8 right half (fp8); W -> Wcat_f8
//      left half (fp8). First 512 threads zero gb.
__global__ __launch_bounds__(256) void cvt_fuse(
    const float* __restrict__ src, const float* __restrict__ W,
    const float* __restrict__ thk, const float* __restrict__ thq,
    const float* __restrict__ thv,
    unsigned short* __restrict__ src_bf, unsigned char* __restrict__ src_cat_f8,
    unsigned char* __restrict__ Wcat_f8, unsigned char* __restrict__ thkT8,
    unsigned short* __restrict__ thqT, float* __restrict__ gb) {
  const int z = blockIdx.z;
  const int tid = threadIdx.x;
  if (z < 3) {
    __shared__ float tile[64][65];   // pad 65: bank=(c+r)%32 -> max 2-way
    const int bx = blockIdx.x * 64, by = blockIdx.y * 64;
    const int c4 = (tid & 15) * 4, rr = tid >> 4;    // rr 0..15
#pragma unroll
    for (int p = 0; p < 4; ++p) {
      const int r = rr + p * 16;
      const size_t idx = (size_t)(by + r) * D_DIM + bx + c4;
      float4 v = (z == 1) ? *(const float4*)(thq + idx)
                          : *(const float4*)(thk + idx);
      if (z == 2) {
        const float4 w = *(const float4*)(thv + idx);
        v.x -= w.x; v.y -= w.y; v.z -= w.z; v.w -= w.w;
      }
      tile[r][c4 + 0] = v.x; tile[r][c4 + 1] = v.y;
      tile[r][c4 + 2] = v.z; tile[r][c4 + 3] = v.w;
    }
    __syncthreads();
#pragma unroll
    for (int q = 0; q < 4; ++q) {
      const int ro = rr + q * 16;
      // output[bx+ro][by+c4..+3] = in[by+c4..+3][bx+ro] = tile[c4..+3][ro]
      const float a = tile[c4 + 0][ro], b = tile[c4 + 1][ro];
      const float c = tile[c4 + 2][ro], d = tile[c4 + 3][ro];
      if (z == 0)
        *(uchar4*)(thkT8 + (size_t)(bx + ro) * 2048 + by + c4) =
            make_uchar4(f2f8(a), f2f8(b), f2f8(c), f2f8(d));
      else if (z == 1)
        *(ushort4*)(thqT + (size_t)(bx + ro) * 2048 + by + c4) =
            make_ushort4(f2bf(a), f2bf(b), f2bf(c), f2bf(d));
      else
        *(uchar4*)(Wcat_f8 + (size_t)(bx + ro) * 4096 + 2048 + by + c4) =
            make_uchar4(f2f8(a), f2f8(b), f2f8(c), f2f8(d));
    }
  } else {
    const int linb = (z - 3) * 1024 + blockIdx.y * 32 + blockIdx.x;
    const int i = linb * 256 + tid;                // 0 .. 3145727
    if (i < 512) ((float4*)gb)[i] = (float4){0.f, 0.f, 0.f, 0.f};
    if (i < 2097152) {
      const int m = i >> 9, c = i & 511;
      const float4 v = ((const float4*)src)[i];
      ((ushort4*)src_bf)[i] = make_ushort4(f2bf(v.x), f2bf(v.y), f2bf(v.z), f2bf(v.w));
      *(uchar4*)(src_cat_f8 + (size_t)m * 4096 + 2048 + c * 4) =
          make_uchar4(f2f8(v.x), f2f8(v.y), f2f8(v.z), f2f8(v.w));
    } else {
      const int j = i - 2097152;
      const int n = j >> 9, c = j & 511;
      const float4 v = ((const float4*)W)[j];
      *(uchar4*)(Wcat_f8 + (size_t)n * 4096 + c * 4) =
          make_uchar4(f2f8(v.x), f2f8(v.y), f2f8(v.z), f2f8(v.w));
    }
  }
}

extern "C" void kernel_launch(void* const* d_in, const int* in_sizes, int n_in,
                              void* d_out, int out_size, void* d_ws, size_t ws_size,
                              hipStream_t stream) {
  const float* src = (const float*)d_in[0];
  const float* thk = (const float*)d_in[1];
  const float* thq = (const float*)d_in[2];
  const float* thv = (const float*)d_in[3];
  const float* W   = (const float*)d_in[4];
  const float* bv  = (const float*)d_in[5];
  const float* lrw = (const float*)d_in[6];
  const float* lrb = (const float*)d_in[7];
  float* out = (float*)d_out;

  char* ws = (char*)d_ws;
  const size_t MB = 1024 * 1024;
  unsigned short* src_bf     = (unsigned short*)(ws + 0);        // 16 MB bf16 [4096x2048]
  unsigned char*  src_cat_f8 = (unsigned char*)(ws + 16 * MB);   // 16 MB fp8 [4096x4096] (train|src)
  unsigned char*  Wcat_f8    = (unsigned char*)(ws + 32 * MB);   //  8 MB fp8 [2048x4096] (W | thk-thv ^T)
  unsigned char*  thkT8      = (unsigned char*)(ws + 40 * MB);   //  4 MB fp8
  unsigned short* thqT       = (unsigned short*)(ws + 44 * MB);  //  8 MB bf16
  unsigned char*  trainT8    = (unsigned char*)(ws + 52 * MB);   //  8 MB fp8 [2048x4096]
  unsigned short* testv      = (unsigned short*)(ws + 60 * MB);  // 16 MB bf16
  unsigned char*  errT8      = (unsigned char*)(ws + 76 * MB);   //  8 MB fp8 [2048x4096]
  unsigned short* WnewBf     = (unsigned short*)(ws + 84 * MB);  //  8 MB bf16
  float*          P0         = (float*)(ws + 92 * MB);           // 16 MB f32
  float*          P1         = (float*)(ws + 108 * MB);          // 16 MB f32
  float*          gb         = (float*)(ws + 124 * MB);          //  8 KB

  cvt_fuse<<<dim3(32, 32, 15), 256, 0, stream>>>(src, W, thk, thq, thv, src_bf,
                                                 src_cat_f8, Wcat_f8, thkT8,
                                                 thqT, gb);

  gemm_train_f8<<<dim3(16, 16), 512, 0, stream>>>(src_cat_f8 + 2048, thkT8,
                                                  src_cat_f8, trainT8);
  gemm_test<<<dim3(16, 16), 512, 0, stream>>>(src_bf, thqT, testv);
  gemm_err_f8<<<dim3(16, 16), 512, 0, stream>>>(src_cat_f8, Wcat_f8, bv, errT8, gb);
  gemm_gw_f8<<<dim3(16, 8, 2), 512, 0, stream>>>(errT8, trainT8, P0, P1);
  wnew_reduce<<<4096, 256, 0, stream>>>(P0, P1, W, lrw, WnewBf);
  gemm_out<<<dim3(16, 16), 512, 0, stream>>>(testv, WnewBf, bv, lrb, gb, out);
}

// Round 9
// 313.120 us; speedup vs baseline: 1.0117x; 1.0117x over previous
//
#include <hip/hip_runtime.h>
#include <hip/hip_bf16.h>
#include <hip/hip_fp8.h>
#include <stdint.h>

#define D_DIM 2048
#define B_TOK 4096
#define COEF (2.0f / 8388608.0f)   // 2/(B*D)

typedef __bf16 bf16x8 __attribute__((ext_vector_type(8)));
typedef float  f32x4  __attribute__((ext_vector_type(4)));
typedef int    i32x8  __attribute__((ext_vector_type(8)));

__device__ __forceinline__ unsigned short f2bf(float f) {
  return __builtin_bit_cast(unsigned short, (__bf16)f);
}
__device__ __forceinline__ float bf2f(unsigned short u) {
  return (float)__builtin_bit_cast(__bf16, u);
}
__device__ __forceinline__ unsigned char f2f8(float f) {
  __hip_fp8_e4m3 v(f);            // OCP e4m3fn, RNE + satfinite
  return v.__x;
}

// async global->LDS, 16B per lane; LDS dest = wave-uniform base + lane*16
__device__ __forceinline__ void async16(const void* g, void* l) {
  __builtin_amdgcn_global_load_lds(
      (__attribute__((address_space(1))) void*)(g),
      (__attribute__((address_space(3))) void*)(l),
      16, 0, 0);
}

// ---------------------------------------------------------------------------
// BF16 big-tile core, single-barrier counted-wait schedule (BEST measured):
// C[256x128], BK=64, 8 waves (4M x 2N), per-wave 64x64 = 4x4 of
// mfma_f32_16x16x32_bf16.
// Per K-tile: issue ALL 16 ds_read_b128 (slice0 8, slice1 8) -> stage kt+2
// -> lgkmcnt(8) -> 16 MFMA (slice0, overlapping slice1's LDS drain)
// -> lgkmcnt(0) -> 16 MFMA (slice1) -> vmcnt(6) -> ONE s_barrier.
// ---------------------------------------------------------------------------
__device__ __forceinline__ void gemm_core_256(const unsigned short* __restrict__ Ablk,
                                              const unsigned short* __restrict__ Bblk,
                                              const int lda, const int ldb, const int KC,
                                              unsigned short* As, unsigned short* Bs,
                                              f32x4 acc[4][4]) {
  const int tid  = threadIdx.x;
  const int lane = tid & 63;
  const int wv   = tid >> 6;          // 0..7
  const int wm   = wv >> 1;           // 0..3 (M)
  const int wn   = wv & 1;            // 0..1 (N)
  const int t    = lane & 15;
  const int quad = lane >> 4;
  const int lrow = lane >> 3;
  const int kq   = lane & 7;
  const int kqs  = kq ^ lrow;

  const int nk = KC >> 6;

  auto stageA2 = [&](int buf, int kt, int l0) {   // 2 A-segments
    const int k0 = kt << 6;
    unsigned short* Ad = As + buf * 16384;
#pragma unroll
    for (int l = l0; l < l0 + 2; ++l) {
      const int seg = wv * 4 + l;
      const int r   = seg * 8 + lrow;
      async16(Ablk + (size_t)r * lda + k0 + kqs * 8, Ad + seg * 512);
    }
  };
  auto stageB1 = [&](int buf, int kt, int l) {    // 1 B-segment
    const int k0 = kt << 6;
    unsigned short* Bd = Bs + buf * 8192;
    const int seg = wv * 2 + l;
    const int r   = seg * 8 + lrow;
    async16(Bblk + (size_t)r * ldb + k0 + kqs * 8, Bd + seg * 512);
  };

  // prologue: stage tiles 0 and 1 (6 loads each), publish tile 0
  stageA2(0, 0, 0); stageA2(0, 0, 2); stageB1(0, 0, 0); stageB1(0, 0, 1);
  if (nk > 1) { stageA2(1, 1, 0); stageA2(1, 1, 2); stageB1(1, 1, 0); stageB1(1, 1, 1); }
  if (nk > 1) asm volatile("s_waitcnt vmcnt(6)" ::: "memory");
  else        asm volatile("s_waitcnt vmcnt(0)" ::: "memory");
  __builtin_amdgcn_s_barrier();

  int cur = 0;
  for (int kt = 0; kt < nk; ++kt) {
    const unsigned short* Ac = As + cur * 16384;
    const unsigned short* Bc = Bs + cur * 8192;
    const int nb = (cur >= 1) ? cur - 1 : 2;      // (cur+2)%3
    const bool pf = (kt + 2 < nk);

    bf16x8 af0[4], bf0[4], af1[4], bf1[4];
    // slice 0 reads (first 8 lgkm ops)
#pragma unroll
    for (int i = 0; i < 4; ++i) {
      const int rm = wm * 64 + i * 16 + t;
      const int rn = wn * 64 + i * 16 + t;
      af0[i] = *(const bf16x8*)(Ac + rm * 64 + ((quad) ^ (rm & 7)) * 8);
      bf0[i] = *(const bf16x8*)(Bc + rn * 64 + ((quad) ^ (rn & 7)) * 8);
    }
    __builtin_amdgcn_sched_barrier(0);
    // slice 1 reads (next 8 lgkm ops)
#pragma unroll
    for (int i = 0; i < 4; ++i) {
      const int rm = wm * 64 + i * 16 + t;
      const int rn = wn * 64 + i * 16 + t;
      af1[i] = *(const bf16x8*)(Ac + rm * 64 + ((4 + quad) ^ (rm & 7)) * 8);
      bf1[i] = *(const bf16x8*)(Bc + rn * 64 + ((4 + quad) ^ (rn & 7)) * 8);
    }
    __builtin_amdgcn_sched_barrier(0);
    if (pf) { stageA2(nb, kt + 2, 0); stageA2(nb, kt + 2, 2);
              stageB1(nb, kt + 2, 0); stageB1(nb, kt + 2, 1); }
    __builtin_amdgcn_sched_barrier(0);
    asm volatile("s_waitcnt lgkmcnt(8)" ::: "memory");   // slice0 landed
    __builtin_amdgcn_sched_barrier(0);
    __builtin_amdgcn_s_setprio(1);
#pragma unroll
    for (int i = 0; i < 4; ++i)
#pragma unroll
      for (int j = 0; j < 4; ++j)
        acc[i][j] = __builtin_amdgcn_mfma_f32_16x16x32_bf16(af0[i], bf0[j], acc[i][j], 0, 0, 0);
    __builtin_amdgcn_s_setprio(0);
    __builtin_amdgcn_sched_barrier(0);
    asm volatile("s_waitcnt lgkmcnt(0)" ::: "memory");   // slice1 landed
    __builtin_amdgcn_sched_barrier(0);
    __builtin_amdgcn_s_setprio(1);
#pragma unroll
    for (int i = 0; i < 4; ++i)
#pragma unroll
      for (int j = 0; j < 4; ++j)
        acc[i][j] = __builtin_amdgcn_mfma_f32_16x16x32_bf16(af1[i], bf1[j], acc[i][j], 0, 0, 0);
    __builtin_amdgcn_s_setprio(0);
    __builtin_amdgcn_sched_barrier(0);
    // publish tile kt+1 (own loads), leave kt+2's 6 in flight
    if (pf)               asm volatile("s_waitcnt vmcnt(6)" ::: "memory");
    else if (kt + 1 < nk) asm volatile("s_waitcnt vmcnt(0)" ::: "memory");
    __builtin_amdgcn_s_barrier();
    cur = (cur == 2) ? 0 : cur + 1;
  }
}

// 256x128 prologue: grid dim3(16,16), 512 threads, XCD-bijective swizzle.
#define GEMM_PROLOGUE256(AP, BP, LDAv, LDBv, KCv)                              \
  __shared__ __align__(16) unsigned short As[3 * 16384];                       \
  __shared__ __align__(16) unsigned short Bs[3 * 8192];                        \
  const int lin = blockIdx.y * 16 + blockIdx.x;                                \
  const int swz = (lin & 7) * 32 + (lin >> 3);                                 \
  const int bx = swz & 15, by = swz >> 4;                                      \
  const unsigned short* Ablk = (AP) + (size_t)by * 256 * (LDAv);               \
  const unsigned short* Bblk = (BP) + (size_t)bx * 128 * (LDBv);               \
  f32x4 acc[4][4];                                                             \
  _Pragma("unroll") for (int i = 0; i < 4; ++i)                                \
  _Pragma("unroll") for (int j = 0; j < 4; ++j)                                \
      acc[i][j] = (f32x4){0.f, 0.f, 0.f, 0.f};                                 \
  gemm_core_256(Ablk, Bblk, (LDAv), (LDBv), (KCv), As, Bs, acc);               \
  const int lane = threadIdx.x & 63;                                           \
  const int wv = threadIdx.x >> 6;                                             \
  const int wm = wv >> 1, wn = wv & 1;                                         \
  const int t = lane & 15, quad = lane >> 4;                                   \
  const int gm_base = by * 256 + wm * 64;                                      \
  const int gn_base = bx * 128 + wn * 64;

// ---------------------------------------------------------------------------
// FP8 MX big-tile core, single-barrier counted-wait schedule + CONFLICT-FREE
// chunk map {quad^x, (4+quad)^x} (K-permutation applied to both A and B =>
// MFMA dot product unchanged; scale=1 everywhere).
// ---------------------------------------------------------------------------
__device__ __forceinline__ void gemm_core_f8_256(const unsigned char* __restrict__ Ablk,
                                                 const unsigned char* __restrict__ Bblk,
                                                 const int lda, const int ldb, const int KC,
                                                 unsigned char* As, unsigned char* Bs,
                                                 f32x4 acc[4][4]) {
  const int tid  = threadIdx.x;
  const int lane = tid & 63;
  const int wv   = tid >> 6;          // 0..7
  const int wm   = wv >> 1;           // 0..3 (M)
  const int wn   = wv & 1;            // 0..1 (N)
  const int t    = lane & 15;
  const int quad = lane >> 4;
  const int lrow = lane >> 3;
  const int kq   = lane & 7;
  const int kqs  = kq ^ lrow;

  const int nk = KC >> 7;

  auto stageA2 = [&](int buf, int kt, int l0) {   // 2 A-segments (8 rows each)
    const int k0 = kt << 7;
    unsigned char* Ad = As + buf * 32768;
#pragma unroll
    for (int l = l0; l < l0 + 2; ++l) {
      const int seg = wv * 4 + l;                 // 32 segs total
      const int r   = seg * 8 + lrow;
      async16(Ablk + (size_t)r * lda + k0 + kqs * 16, Ad + seg * 1024);
    }
  };
  auto stageB1 = [&](int buf, int kt, int l) {    // 1 B-segment
    const int k0 = kt << 7;
    unsigned char* Bd = Bs + buf * 16384;
    const int seg = wv * 2 + l;                   // 16 segs total
    const int r   = seg * 8 + lrow;
    async16(Bblk + (size_t)r * ldb + k0 + kqs * 16, Bd + seg * 1024);
  };

  // Conflict-free fragment read: chunks quad^x and (4+quad)^x of a 128B row.
  auto readF = [&](const unsigned char* base, int x) -> i32x8 {
    const uint4 lo = *(const uint4*)(base + ((quad      ) ^ x) * 16);
    const uint4 hi = *(const uint4*)(base + ((4 + quad  ) ^ x) * 16);
    return (i32x8){(int)lo.x, (int)lo.y, (int)lo.z, (int)lo.w,
                   (int)hi.x, (int)hi.y, (int)hi.z, (int)hi.w};
  };

  // prologue: stage tiles 0 and 1 (6 loads each), publish tile 0
  stageA2(0, 0, 0); stageA2(0, 0, 2); stageB1(0, 0, 0); stageB1(0, 0, 1);
  if (nk > 1) { stageA2(1, 1, 0); stageA2(1, 1, 2); stageB1(1, 1, 0); stageB1(1, 1, 1); }
  if (nk > 1) asm volatile("s_waitcnt vmcnt(6)" ::: "memory");
  else        asm volatile("s_waitcnt vmcnt(0)" ::: "memory");
  __builtin_amdgcn_s_barrier();

  int cur = 0;
  for (int kt = 0; kt < nk; ++kt) {
    const unsigned char* Ac = As + cur * 32768;
    const unsigned char* Bc = Bs + cur * 16384;
    const int nb = (cur >= 1) ? cur - 1 : 2;      // (cur+2)%3
    const bool pf = (kt + 2 < nk);

    i32x8 af[4], bq0, bq1, bq2, bq3;
    // group 0: A-frags + B j=0,1 (12 lgkm ops)
#pragma unroll
    for (int i = 0; i < 4; ++i) {
      const int rm = wm * 64 + i * 16 + t;
      af[i] = readF(Ac + rm * 128, rm & 7);
    }
    {
      const int rn0 = wn * 64 + 0 * 16 + t;
      bq0 = readF(Bc + rn0 * 128, rn0 & 7);
      const int rn1 = wn * 64 + 1 * 16 + t;
      bq1 = readF(Bc + rn1 * 128, rn1 & 7);
    }
    __builtin_amdgcn_sched_barrier(0);
    // group 1: B j=2,3 (4 lgkm ops)
    {
      const int rn2 = wn * 64 + 2 * 16 + t;
      bq2 = readF(Bc + rn2 * 128, rn2 & 7);
      const int rn3 = wn * 64 + 3 * 16 + t;
      bq3 = readF(Bc + rn3 * 128, rn3 & 7);
    }
    __builtin_amdgcn_sched_barrier(0);
    if (pf) { stageA2(nb, kt + 2, 0); stageA2(nb, kt + 2, 2);
              stageB1(nb, kt + 2, 0); stageB1(nb, kt + 2, 1); }
    __builtin_amdgcn_sched_barrier(0);
    asm volatile("s_waitcnt lgkmcnt(4)" ::: "memory");   // group0 landed
    __builtin_amdgcn_sched_barrier(0);
    __builtin_amdgcn_s_setprio(1);
#pragma unroll
    for (int i = 0; i < 4; ++i) {
      acc[i][0] = __builtin_amdgcn_mfma_scale_f32_16x16x128_f8f6f4(
          af[i], bq0, acc[i][0], 0, 0, 0, 127, 0, 127);
      acc[i][1] = __builtin_amdgcn_mfma_scale_f32_16x16x128_f8f6f4(
          af[i], bq1, acc[i][1], 0, 0, 0, 127, 0, 127);
    }
    __builtin_amdgcn_s_setprio(0);
    __builtin_amdgcn_sched_barrier(0);
    asm volatile("s_waitcnt lgkmcnt(0)" ::: "memory");   // group1 landed
    __builtin_amdgcn_sched_barrier(0);
    __builtin_amdgcn_s_setprio(1);
#pragma unroll
    for (int i = 0; i < 4; ++i) {
      acc[i][2] = __builtin_amdgcn_mfma_scale_f32_16x16x128_f8f6f4(
          af[i], bq2, acc[i][2], 0, 0, 0, 127, 0, 127);
      acc[i][3] = __builtin_amdgcn_mfma_scale_f32_16x16x128_f8f6f4(
          af[i], bq3, acc[i][3], 0, 0, 0, 127, 0, 127);
    }
    __builtin_amdgcn_s_setprio(0);
    __builtin_amdgcn_sched_barrier(0);
    if (pf)               asm volatile("s_waitcnt vmcnt(6)" ::: "memory");
    else if (kt + 1 < nk) asm volatile("s_waitcnt vmcnt(0)" ::: "memory");
    __builtin_amdgcn_s_barrier();
    cur = (cur == 2) ? 0 : cur + 1;
  }
}

// 256x128 fp8 prologue: 512 threads, grid-size-generic XCD-bijective swizzle
// (all fp8 grids have gridDim.x == 16 and nwg % 8 == 0).
#define GEMM8_PROLOGUE256(AP, BP, LDAv, LDBv, KCv)                             \
  __shared__ __align__(16) unsigned char As8[3 * 32768];                       \
  __shared__ __align__(16) unsigned char Bs8[3 * 16384];                       \
  const int nwg = gridDim.x * gridDim.y;                                       \
  const int lin = blockIdx.y * 16 + blockIdx.x;                                \
  const int swz = (lin & 7) * (nwg >> 3) + (lin >> 3);                         \
  const int bx = swz & 15, by = swz >> 4;                                      \
  const unsigned char* Ablk = (AP) + (size_t)by * 256 * (LDAv);                \
  const unsigned char* Bblk = (BP) + (size_t)bx * 128 * (LDBv);                \
  f32x4 acc[4][4];                                                             \
  _Pragma("unroll") for (int i = 0; i < 4; ++i)                                \
  _Pragma("unroll") for (int j = 0; j < 4; ++j)                                \
      acc[i][j] = (f32x4){0.f, 0.f, 0.f, 0.f};                                 \
  gemm_core_f8_256(Ablk, Bblk, (LDAv), (LDBv), (KCv), As8, Bs8, acc);          \
  const int lane = threadIdx.x & 63;                                           \
  const int wv = threadIdx.x >> 6;                                             \
  const int wm = wv >> 1, wn = wv & 1;                                         \
  const int t = lane & 15, quad = lane >> 4;                                   \
  const int gm_base = by * 256 + wm * 64;                                      \
  const int gn_base = bx * 128 + wn * 64;

// GEMM-train (fp8): train = src @ thk^T. A = src_cat_f8 right half (lda 4096).
// Writes train fp8 into src_cat_f8 LEFT half + trainT8 (LDS-transposed).
__global__ __launch_bounds__(512, 2) void gemm_train_f8(
    const unsigned char* __restrict__ srcA,     // src_cat_f8 + 2048
    const unsigned char* __restrict__ thkT8,    // ld 2048
    unsigned char* __restrict__ src_cat_f8,
    unsigned char* __restrict__ trainT8) {
  GEMM8_PROLOGUE256(srcA, thkT8, 4096, 2048, 2048)
  unsigned char* scr = As8 + wv * 2304;   // per-wave 32 x 72 B scratch
#pragma unroll
  for (int p = 0; p < 2; ++p) {
#pragma unroll
    for (int jl = 0; jl < 2; ++jl) {
      const int j = p * 2 + jl;
      const int gn = gn_base + j * 16 + t;
#pragma unroll
      for (int i = 0; i < 4; ++i) {
        const int gm0 = gm_base + i * 16 + quad * 4;
        uchar4 pk = make_uchar4(f2f8(acc[i][j][0]), f2f8(acc[i][j][1]),
                                f2f8(acc[i][j][2]), f2f8(acc[i][j][3]));
        src_cat_f8[(size_t)(gm0 + 0) * 4096 + gn] = pk.x;
        src_cat_f8[(size_t)(gm0 + 1) * 4096 + gn] = pk.y;
        src_cat_f8[(size_t)(gm0 + 2) * 4096 + gn] = pk.z;
        src_cat_f8[(size_t)(gm0 + 3) * 4096 + gn] = pk.w;
        *(uchar4*)(scr + (jl * 16 + t) * 72 + i * 16 + quad * 4) = pk;
      }
    }
    __syncthreads();
    const int row = lane >> 3, chunk = lane & 7;
#pragma unroll
    for (int q = 0; q < 4; ++q) {
      const int rr = q * 8 + row;
      const uint2 v = *(const uint2*)(scr + rr * 72 + chunk * 8);
      *(uint2*)(trainT8 + (size_t)(gn_base + p * 32 + rr) * B_TOK + gm_base + chunk * 8) = v;
    }
    __syncthreads();
  }
}

// GEMM-test (bf16, 256x128): test = src @ thq^T -> testv (ld 2048)
__global__ __launch_bounds__(512, 2) void gemm_test(
    const unsigned short* __restrict__ src_bf,
    const unsigned short* __restrict__ thqT,
    unsigned short* __restrict__ testv) {
  GEMM_PROLOGUE256(src_bf, thqT, 2048, 2048, 2048)
#pragma unroll
  for (int i = 0; i < 4; ++i) {
#pragma unroll
    for (int j = 0; j < 4; ++j) {
      const int gm0 = gm_base + i * 16 + quad * 4;
      const int gn  = gn_base + j * 16 + t;
#pragma unroll
      for (int r = 0; r < 4; ++r)
        testv[(size_t)(gm0 + r) * D_DIM + gn] = f2bf(acc[i][j][r]);
    }
  }
}

// GEMM-err (fp8, K=4096): err = [train|src] @ [W | (thk-thv)^T]^T + b.
// Stored transposed errT8[D, B_TOK] fp8 + gb column sums.
__global__ __launch_bounds__(512, 2) void gemm_err_f8(
    const unsigned char* __restrict__ src_cat_f8,
    const unsigned char* __restrict__ Wcat_f8,
    const float* __restrict__ bvec,
    unsigned char* __restrict__ errT8,
    float* __restrict__ gb) {
  GEMM8_PROLOGUE256(src_cat_f8, Wcat_f8, 4096, 4096, 4096)
  unsigned char* scr = As8 + wv * 2304;
#pragma unroll
  for (int p = 0; p < 2; ++p) {
#pragma unroll
    for (int jl = 0; jl < 2; ++jl) {
      const int j = p * 2 + jl;
      const int gn = gn_base + j * 16 + t;
      const float bias = bvec[gn];
      float cs = 0.f;
#pragma unroll
      for (int i = 0; i < 4; ++i) {
        const float e0 = acc[i][j][0] + bias, e1 = acc[i][j][1] + bias;
        const float e2 = acc[i][j][2] + bias, e3 = acc[i][j][3] + bias;
        *(uchar4*)(scr + (jl * 16 + t) * 72 + i * 16 + quad * 4) =
            make_uchar4(f2f8(e0), f2f8(e1), f2f8(e2), f2f8(e3));
        cs += e0 + e1 + e2 + e3;
      }
      cs += __shfl_xor(cs, 16);
      cs += __shfl_xor(cs, 32);
      if (quad == 0) atomicAdd(&gb[gn], cs);
    }
    __syncthreads();
    const int row = lane >> 3, chunk = lane & 7;
#pragma unroll
    for (int q = 0; q < 4; ++q) {
      const int rr = q * 8 + row;
      const uint2 v = *(const uint2*)(scr + rr * 72 + chunk * 8);
      *(uint2*)(errT8 + (size_t)(gn_base + p * 32 + rr) * B_TOK + gm_base + chunk * 8) = v;
    }
    __syncthreads();
  }
}

// GEMM-gW (fp8, split-K=2): P_z = errT[:, z*2048:+2048] @ trainT[:, same]^T
__global__ __launch_bounds__(512, 2) void gemm_gw_f8(
    const unsigned char* __restrict__ errT8,
    const unsigned char* __restrict__ trainT8,
    float* __restrict__ P0, float* __restrict__ P1) {
  const int z = blockIdx.z;
  const unsigned char* Abase = errT8 + z * 2048;
  const unsigned char* Bbase = trainT8 + z * 2048;
  GEMM8_PROLOGUE256(Abase, Bbase, B_TOK, B_TOK, 2048)
  float* P = (z == 0) ? P0 : P1;
#pragma unroll
  for (int i = 0; i < 4; ++i) {
#pragma unroll
    for (int j = 0; j < 4; ++j) {
      const int gm0 = gm_base + i * 16 + quad * 4;
      const int gn  = gn_base + j * 16 + t;
#pragma unroll
      for (int r = 0; r < 4; ++r)
        P[(size_t)(gm0 + r) * D_DIM + gn] = acc[i][j][r];
    }
  }
}

// Reduce partials + SGD update: Wnew = bf16(W - lr_w * COEF * (P0+P1))
__global__ __launch_bounds__(256) void wnew_reduce(
    const float* __restrict__ P0, const float* __restrict__ P1,
    const float* __restrict__ W, const float* __restrict__ lr_w,
    unsigned short* __restrict__ Wnew) {
  const int i = blockIdx.x * 256 + threadIdx.x;
  const float4 p0 = ((const float4*)P0)[i];
  const float4 p1 = ((const float4*)P1)[i];
  const float4 w  = ((const float4*)W)[i];
  const float4 l  = ((const float4*)lr_w)[i];
  ((ushort4*)Wnew)[i] = make_ushort4(
      f2bf(w.x - l.x * (COEF * (p0.x + p1.x))),
      f2bf(w.y - l.y * (COEF * (p0.y + p1.y))),
      f2bf(w.z - l.z * (COEF * (p0.z + p1.z))),
      f2bf(w.w - l.w * (COEF * (p0.w + p1.w))));
}

// GEMM-out (bf16, 256x128): z = test @ Wnew^T + b_new + test, b_new inline
__global__ __launch_bounds__(512, 2) void gemm_out(
    const unsigned short* __restrict__ testv,
    const unsigned short* __restrict__ Wnew,
    const float* __restrict__ bvec,
    const float* __restrict__ lr_b,
    const float* __restrict__ gb,
    float* __restrict__ out) {
  GEMM_PROLOGUE256(testv, Wnew, 2048, 2048, 2048)
#pragma unroll
  for (int j = 0; j < 4; ++j) {
    const int gn = gn_base + j * 16 + t;
    const float bias = bvec[gn] - lr_b[gn] * (COEF * gb[gn]);
#pragma unroll
    for (int i = 0; i < 4; ++i) {
      const int gm0 = gm_base + i * 16 + quad * 4;
#pragma unroll
      for (int r = 0; r < 4; ++r) {
        const size_t idx = (size_t)(gm0 + r) * D_DIM + gn;
        out[idx] = acc[i][j][r] + bias + bf2f(testv[idx]);
      }
    }
  }
}

// Fused conversions (one launch, grid dim3(32,32,15), 256 threads):
// z<3: transpose+convert, TALL-TILE layout: 256 input-rows x 16 input-cols.
//   Each thread owns a 4x4 block: 4 float4 loads (64B cacheline segments),
//   converts in registers, packs COLUMN-major u32/uint2 words (4 rows/word)
//   into LDS, then each lane does one uint4 LDS read + one 16B global store:
//   a 16/32-lane group emits one fully-contiguous 256B/512B output-row
//   segment. z=0: thk^T->thkT8 fp8; z=1: thq^T->thqT bf16;
//   z=2: (thk-thv)^T -> Wcat_f8 right half fp8.
// z>=3: elementwise (12 slices x 1024 blocks): src -> src_bf (bf16) +
//   src_cat_f8 right half (fp8); W -> Wcat_f8 left half (fp8). First 512
//   threads zero gb.
__global__ __launch_bounds__(256) void cvt_fuse(
    const float* __restrict__ src, const float* __restrict__ W,
    const float* __restrict__ thk, const float* __restrict__ thq,
    const float* __restrict__ thv,
    unsigned short* __restrict__ src_bf, unsigned char* __restrict__ src_cat_f8,
    unsigned char* __restrict__ Wcat_f8, unsigned char* __restrict__ thkT8,
    unsigned short* __restrict__ thqT, float* __restrict__ gb) {
  const int z = blockIdx.z;
  const int tid = threadIdx.x;
  if (z < 3) {
    // T32: fp8 path, [16 cols][68 u32] (stride 272B, 16B-mult); only 64 used.
    // T64: bf16 path, [16 cols][66 uint2] (stride 528B, 16B-mult).
    __shared__ __align__(16) unsigned int Tbuf[2112];   // 8448B, fits both
    unsigned int* T32 = Tbuf;
    uint2* T64 = (uint2*)Tbuf;

    const int blk = blockIdx.y * 32 + blockIdx.x;       // 0..1023
    const int Rbase = (blk & 7) * 256;                  // input row tile
    const int Cbase = (blk >> 3) * 16;                  // input col tile
    const int tr = tid >> 2;                            // 0..63 (row quads)
    const int tc = tid & 3;                             // 0..3  (col quads)

    // load 4x4 block rows 4tr..+3, cols Cbase+4tc..+3
    float4 v[4];
#pragma unroll
    for (int i = 0; i < 4; ++i) {
      const size_t idx = (size_t)(Rbase + 4 * tr + i) * D_DIM + Cbase + 4 * tc;
      v[i] = (z == 1) ? *(const float4*)(thq + idx)
                      : *(const float4*)(thk + idx);
      if (z == 2) {
        const float4 w = *(const float4*)(thv + idx);
        v[i].x -= w.x; v[i].y -= w.y; v[i].z -= w.z; v[i].w -= w.w;
      }
    }
    if (z == 1) {
      // bf16: per col j, 4 rows -> uint2 {r0|r1<<16, r2|r3<<16}
#pragma unroll
      for (int j = 0; j < 4; ++j) {
        const float a = (j == 0) ? v[0].x : (j == 1) ? v[0].y : (j == 2) ? v[0].z : v[0].w;
        const float b = (j == 0) ? v[1].x : (j == 1) ? v[1].y : (j == 2) ? v[1].z : v[1].w;
        const float c = (j == 0) ? v[2].x : (j == 1) ? v[2].y : (j == 2) ? v[2].z : v[2].w;
        const float d = (j == 0) ? v[3].x : (j == 1) ? v[3].y : (j == 2) ? v[3].z : v[3].w;
        uint2 w2;
        w2.x = (unsigned)f2bf(a) | ((unsigned)f2bf(b) << 16);
        w2.y = (unsigned)f2bf(c) | ((unsigned)f2bf(d) << 16);
        T64[(4 * tc + j) * 66 + tr] = w2;
      }
      __syncthreads();
      // store: out row = Cbase + c (16 rows), 512B each = 32 lanes x 16B
#pragma unroll
      for (int q = 0; q < 2; ++q) {
        const int c = (tid >> 5) + 8 * q;               // 0..15
        const int o = tid & 31;                         // 0..31
        const uint4 val = *(const uint4*)&T64[c * 66 + o * 2];
        *(uint4*)(thqT + (size_t)(Cbase + c) * 2048 + Rbase + o * 8) = val;
      }
    } else {
      // fp8: per col j, 4 rows -> u32 bytes r0|r1|r2|r3 (LE)
#pragma unroll
      for (int j = 0; j < 4; ++j) {
        const float a = (j == 0) ? v[0].x : (j == 1) ? v[0].y : (j == 2) ? v[0].z : v[0].w;
        const float b = (j == 0) ? v[1].x : (j == 1) ? v[1].y : (j == 2) ? v[1].z : v[1].w;
        const float c = (j == 0) ? v[2].x : (j == 1) ? v[2].y : (j == 2) ? v[2].z : v[2].w;
        const float d = (j == 0) ? v[3].x : (j == 1) ? v[3].y : (j == 2) ? v[3].z : v[3].w;
        const unsigned w4 = (unsigned)f2f8(a) | ((unsigned)f2f8(b) << 8) |
                            ((unsigned)f2f8(c) << 16) | ((unsigned)f2f8(d) << 24);
        T32[(4 * tc + j) * 68 + tr] = w4;
      }
      __syncthreads();
      // store: out row = Cbase + c (16 rows), 256B each = 16 lanes x 16B
      const int c = tid >> 4;                           // 0..15
      const int o = tid & 15;                           // 0..15
      const uint4 val = *(const uint4*)&T32[c * 68 + o * 4];
      if (z == 0)
        *(uint4*)(thkT8 + (size_t)(Cbase + c) * 2048 + Rbase + o * 16) = val;
      else
        *(uint4*)(Wcat_f8 + (size_t)(Cbase + c) * 4096 + 2048 + Rbase + o * 16) = val;
    }
  } else {
    const int linb = (z - 3) * 1024 + blockIdx.y * 32 + blockIdx.x;
    const int i = linb * 256 + tid;                // 0 .. 3145727
    if (i < 512) ((float4*)gb)[i] = (float4){0.f, 0.f, 0.f, 0.f};
    if (i < 2097152) {
      const int m = i >> 9, c = i & 511;
      const float4 v = ((const float4*)src)[i];
      ((ushort4*)src_bf)[i] = make_ushort4(f2bf(v.x), f2bf(v.y), f2bf(v.z), f2bf(v.w));
      *(uchar4*)(src_cat_f8 + (size_t)m * 4096 + 2048 + c * 4) =
          make_uchar4(f2f8(v.x), f2f8(v.y), f2f8(v.z), f2f8(v.w));
    } else {
      const int j = i - 2097152;
      const int n = j >> 9, c = j & 511;
      const float4 v = ((const float4*)W)[j];
      *(uchar4*)(Wcat_f8 + (size_t)n * 4096 + c * 4) =
          make_uchar4(f2f8(v.x), f2f8(v.y), f2f8(v.z), f2f8(v.w));
    }
  }
}

extern "C" void kernel_launch(void* const* d_in, const int* in_sizes, int n_in,
                              void* d_out, int out_size, void* d_ws, size_t ws_size,
                              hipStream_t stream) {
  const float* src = (const float*)d_in[0];
  const float* thk = (const float*)d_in[1];
  const float* thq = (const float*)d_in[2];
  const float* thv = (const float*)d_in[3];
  const float* W   = (const float*)d_in[4];
  const float* bv  = (const float*)d_in[5];
  const float* lrw = (const float*)d_in[6];
  const float* lrb = (const float*)d_in[7];
  float* out = (float*)d_out;

  char* ws = (char*)d_ws;
  const size_t MB = 1024 * 1024;
  unsigned short* src_bf     = (unsigned short*)(ws + 0);        // 16 MB bf16 [4096x2048]
  unsigned char*  src_cat_f8 = (unsigned char*)(ws + 16 * MB);   // 16 MB fp8 [4096x4096] (train|src)
  unsigned char*  Wcat_f8    = (unsigned char*)(ws + 32 * MB);   //  8 MB fp8 [2048x4096] (W | thk-thv ^T)
  unsigned char*  thkT8      = (unsigned char*)(ws + 40 * MB);   //  4 MB fp8
  unsigned short* thqT       = (unsigned short*)(ws + 44 * MB);  //  8 MB bf16
  unsigned char*  trainT8    = (unsigned char*)(ws + 52 * MB);   //  8 MB fp8 [2048x4096]
  unsigned short* testv      = (unsigned short*)(ws + 60 * MB);  // 16 MB bf16
  unsigned char*  errT8      = (unsigned char*)(ws + 76 * MB);   //  8 MB fp8 [2048x4096]
  unsigned short* WnewBf     = (unsigned short*)(ws + 84 * MB);  //  8 MB bf16
  float*          P0         = (float*)(ws + 92 * MB);           // 16 MB f32
  float*          P1         = (float*)(ws + 108 * MB);          // 16 MB f32
  float*          gb         = (float*)(ws + 124 * MB);          //  8 KB

  cvt_fuse<<<dim3(32, 32, 15), 256, 0, stream>>>(src, W, thk, thq, thv, src_bf,
                                                 src_cat_f8, Wcat_f8, thkT8,
                                                 thqT, gb);

  gemm_train_f8<<<dim3(16, 16), 512, 0, stream>>>(src_cat_f8 + 2048, thkT8,
                                                  src_cat_f8, trainT8);
  gemm_test<<<dim3(16, 16), 512, 0, stream>>>(src_bf, thqT, testv);
  gemm_err_f8<<<dim3(16, 16), 512, 0, stream>>>(src_cat_f8, Wcat_f8, bv, errT8, gb);
  gemm_gw_f8<<<dim3(16, 8, 2), 512, 0, stream>>>(errT8, trainT8, P0, P1);
  wnew_reduce<<<4096, 256, 0, stream>>>(P0, P1, W, lrw, WnewBf);
  gemm_out<<<dim3(16, 16), 512, 0, stream>>>(testv, WnewBf, bv, lrb, gb, out);
}